// Round 1
// 405.822 us; speedup vs baseline: 1.0145x; 1.0145x over previous
//
#include <hip/hip_runtime.h>
#include <stdint.h>

// Problem constants (reference file)
#define B_TOT 4096
#define SEQ   64
#define Y_DIM 256
#define H_DIM 128
#define E_DIM 32
#define KG_N  8
#define KA_N  20
#define NC_N  50
#define NT_N  5

// K1 (streaming max-pool): thin blocks, 4 rows/block -> 16 waves/CU
#define R1   4
#define NB1  (B_TOT / R1)     // 1024 blocks
// K2 (MLP+heads): fat blocks, 8 rows/block -> amortize W_common 2x more
#define R2   8
#define NB2  (B_TOT / R2)     // 512 blocks

// Fallback fused kernel config (previous best)
#define ROWS 4
#define NBLK (B_TOT / ROWS)

// Output offsets (flat f32, return-order concat)
#define O_COUNTRY 0
#define O_TYPE    (B_TOT * NC_N)                  // 204800
#define O_TASTE   (O_TYPE + B_TOT)                // 208896
#define O_GPRED   (O_TASTE + B_TOT * NT_N)        // 229376
#define O_GTRUE   (O_GPRED + B_TOT * KG_N)        // 262144
#define O_APRED   (O_GTRUE + B_TOT * KG_N)        // 294912
#define O_ATRUE   (O_APRED + B_TOT * KA_N)        // 376832

typedef float f4 __attribute__((ext_vector_type(4)));

__device__ __forceinline__ float sigmoidf_(float x) { return 1.0f / (1.0f + __expf(-x)); }

// ---------------------------------------------------------------------------
// K1: pure-stream max over sequence dim. 268 MB read -> 4 MB write.
// One wave per row; lane owns one float4 -> 1 KiB contiguous per wave-instr.
// ---------------------------------------------------------------------------
__global__ __launch_bounds__(256) void maxpool_k(
    const float* __restrict__ x_enc, float* __restrict__ xpool)
{
    const int t   = threadIdx.x;
    const int row = blockIdx.x * R1 + (t >> 6);
    const int y0  = (t & 63) * 4;
    const float* xp = x_enc + (size_t)row * (SEQ * Y_DIM) + y0;
    f4 m = { -3.4e38f, -3.4e38f, -3.4e38f, -3.4e38f };
    #pragma unroll 8
    for (int s = 0; s < SEQ; ++s) {
        f4 a = __builtin_nontemporal_load((const f4*)(xp + (size_t)s * Y_DIM));
        m.x = fmaxf(m.x, a.x); m.y = fmaxf(m.y, a.y);
        m.z = fmaxf(m.z, a.z); m.w = fmaxf(m.w, a.w);
    }
    *(f4*)(xpool + (size_t)row * Y_DIM + y0) = m;
}

// ---------------------------------------------------------------------------
// K2: y = elu(x@W_common+b), 120 head dots, ragged gathers. 8 rows/block.
// Accumulation order is kept identical to the previous fused kernel.
// ---------------------------------------------------------------------------
__global__ __launch_bounds__(256) void heads_k(
    const float* __restrict__ xpool,
    const int*   __restrict__ grapes,
    const float* __restrict__ grapes_scales,
    const int*   __restrict__ aromas,
    const float* __restrict__ aromas_scales,
    const float* __restrict__ W_common,  const float* __restrict__ b_common,
    const float* __restrict__ W_country, const float* __restrict__ b_country,
    const float* __restrict__ W_type,    const float* __restrict__ b_type,
    const float* __restrict__ W_taste,   const float* __restrict__ b_taste,
    const float* __restrict__ W_aroma,   const float* __restrict__ b_aroma,
    const float* __restrict__ W_grape,   const float* __restrict__ b_grape,
    const float* __restrict__ grapes_emb,
    const float* __restrict__ aroma_emb,
    float*       __restrict__ out)
{
    __shared__ float xs[R2][Y_DIM];            // 8 KB pooled x
    __shared__ float ys[R2][H_DIM];            // 4 KB elu(common)
    __shared__ float yg[R2][E_DIM + 1];
    __shared__ float ya[R2][E_DIM + 1];

    const int t  = threadIdx.x;
    const int b0 = blockIdx.x * R2;

    // ---- stage pooled x: 8 KB coalesced f4 copy ----
    {
        const f4* src = (const f4*)(xpool + (size_t)b0 * Y_DIM);
        f4* dst = (f4*)xs;
        #pragma unroll
        for (int i = 0; i < (R2 * Y_DIM) / (256 * 4); ++i)   // 2 iters
            dst[t + i * 256] = src[t + i * 256];
    }
    __syncthreads();

    // ---- y = elu(x @ W_common + b_common) ----
    // thread = (h-col c, 4-row group). Wave reads 256 B/k of W (coalesced,
    // L1-hot); x via broadcast ds_read_b128.
    {
        const int c  = t & 127;
        const int r0 = (t >> 7) * 4;           // 0 or 4
        float a0 = 0.f, a1 = 0.f, a2 = 0.f, a3 = 0.f;
        const float* Wp = W_common + c;
        #pragma unroll 2
        for (int k = 0; k < Y_DIM; k += 4) {
            f4 x0 = *(const f4*)&xs[r0 + 0][k];
            f4 x1 = *(const f4*)&xs[r0 + 1][k];
            f4 x2 = *(const f4*)&xs[r0 + 2][k];
            f4 x3 = *(const f4*)&xs[r0 + 3][k];
            float w0 = Wp[(size_t)(k + 0) * H_DIM];
            float w1 = Wp[(size_t)(k + 1) * H_DIM];
            float w2 = Wp[(size_t)(k + 2) * H_DIM];
            float w3 = Wp[(size_t)(k + 3) * H_DIM];
            a0 += x0.x * w0; a0 += x0.y * w1; a0 += x0.z * w2; a0 += x0.w * w3;
            a1 += x1.x * w0; a1 += x1.y * w1; a1 += x1.z * w2; a1 += x1.w * w3;
            a2 += x2.x * w0; a2 += x2.y * w1; a2 += x2.z * w2; a2 += x2.w * w3;
            a3 += x3.x * w0; a3 += x3.y * w1; a3 += x3.z * w2; a3 += x3.w * w3;
        }
        const float bb = b_common[c];
        a0 += bb; a1 += bb; a2 += bb; a3 += bb;
        a0 = (a0 > 0.f) ? a0 : (__expf(a0) - 1.f);
        a1 = (a1 > 0.f) ? a1 : (__expf(a1) - 1.f);
        a2 = (a2 > 0.f) ? a2 : (__expf(a2) - 1.f);
        a3 = (a3 > 0.f) ? a3 : (__expf(a3) - 1.f);
        ys[r0 + 0][c] = a0;
        ys[r0 + 1][c] = a1;
        ys[r0 + 2][c] = a2;
        ys[r0 + 3][c] = a3;
    }
    __syncthreads();

    // ---- head dots (120 columns per row) ----
    // c: [0,50) country | 50 type | [51,56) taste | [56,88) grape | [88,120) aroma
    for (int j = t; j < R2 * 120; j += 256) {
        const int row = j / 120;
        const int c   = j - row * 120;
        const float* Wp;
        int stride;
        if (c < 50)       { Wp = W_country + c;        stride = NC_N;  }
        else if (c == 50) { Wp = W_type;               stride = 1;     }
        else if (c < 56)  { Wp = W_taste + (c - 51);   stride = NT_N;  }
        else if (c < 88)  { Wp = W_grape + (c - 56);   stride = E_DIM; }
        else              { Wp = W_aroma + (c - 88);   stride = E_DIM; }
        float acc = 0.f;
        const float* yv = ys[row];
        #pragma unroll 4
        for (int k = 0; k < H_DIM; k += 4) {
            f4 y4 = *(const f4*)&yv[k];
            acc += y4.x * Wp[(size_t)(k + 0) * stride];
            acc += y4.y * Wp[(size_t)(k + 1) * stride];
            acc += y4.z * Wp[(size_t)(k + 2) * stride];
            acc += y4.w * Wp[(size_t)(k + 3) * stride];
        }
        const int b = b0 + row;
        if (c < 50) {
            out[O_COUNTRY + (size_t)b * NC_N + c] = acc + b_country[c];
        } else if (c == 50) {
            out[O_TYPE + b] = sigmoidf_(acc + b_type[0]);
        } else if (c < 56) {
            out[O_TASTE + (size_t)b * NT_N + (c - 51)] = sigmoidf_(acc + b_taste[c - 51]);
        } else if (c < 88) {
            yg[row][c - 56] = acc + b_grape[c - 56];
        } else {
            ya[row][c - 88] = acc + b_aroma[c - 88];
        }
    }
    __syncthreads();

    // ---- ragged gathers ----
    if (t < R2 * KG_N) {                         // 64 grape jobs
        const int row  = t >> 3;
        const int gi   = (b0 + row) * KG_N + (t & 7);
        const int idx  = grapes[gi];
        float pred = 0.f;
        if (idx != 0) {
            const float* ep = grapes_emb + (size_t)idx * E_DIM;
            const float* yv = yg[row];
            float acc = 0.f;
            #pragma unroll
            for (int e = 0; e < E_DIM; e += 4) {
                float4 v = *(const float4*)(ep + e);
                acc += yv[e+0]*v.x + yv[e+1]*v.y + yv[e+2]*v.z + yv[e+3]*v.w;
            }
            pred = sigmoidf_(acc);
        }
        out[O_GPRED + gi] = pred;
        out[O_GTRUE + gi] = grapes_scales[gi];   // scales*(scales!=0) == scales, exact
    } else if (t < R2 * (KG_N + KA_N)) {         // 160 aroma jobs
        const int j    = t - R2 * KG_N;
        const int row  = j / KA_N;
        const int ai   = (b0 + row) * KA_N + (j - row * KA_N);
        const float sc = aromas_scales[ai];
        float pred = 0.f;
        if (sc != 0.f) {
            const int idx = aromas[ai];
            const float* ep = aroma_emb + (size_t)idx * E_DIM;
            const float* yv = ya[row];
            float acc = 0.f;
            #pragma unroll
            for (int e = 0; e < E_DIM; e += 4) {
                float4 v = *(const float4*)(ep + e);
                acc += yv[e+0]*v.x + yv[e+1]*v.y + yv[e+2]*v.z + yv[e+3]*v.w;
            }
            pred = sigmoidf_(acc);
        }
        out[O_APRED + ai] = pred;
        out[O_ATRUE + ai] = sc;
    }
}

// ---------------------------------------------------------------------------
// Fallback: previous fused kernel (used only if ws_size < 4 MB)
// ---------------------------------------------------------------------------
__global__ __launch_bounds__(256) void wine_fused_kernel(
    const float* __restrict__ x_enc,
    const int*   __restrict__ grapes,
    const float* __restrict__ grapes_scales,
    const int*   __restrict__ aromas,
    const float* __restrict__ aromas_scales,
    const float* __restrict__ W_common,  const float* __restrict__ b_common,
    const float* __restrict__ W_country, const float* __restrict__ b_country,
    const float* __restrict__ W_type,    const float* __restrict__ b_type,
    const float* __restrict__ W_taste,   const float* __restrict__ b_taste,
    const float* __restrict__ W_aroma,   const float* __restrict__ b_aroma,
    const float* __restrict__ W_grape,   const float* __restrict__ b_grape,
    const float* __restrict__ grapes_emb,
    const float* __restrict__ aroma_emb,
    float*       __restrict__ out)
{
    __shared__ float xs[ROWS][Y_DIM];
    __shared__ float ys[ROWS][H_DIM];
    __shared__ float yg[ROWS][E_DIM + 1];
    __shared__ float ya[ROWS][E_DIM + 1];

    const int t  = threadIdx.x;
    const int b0 = blockIdx.x * ROWS;

    {
        const int row = t >> 6;
        const int y0  = (t & 63) * 4;
        const float* xp = x_enc + (size_t)(b0 + row) * SEQ * Y_DIM + y0;
        f4 m = { -3.4e38f, -3.4e38f, -3.4e38f, -3.4e38f };
        #pragma unroll 8
        for (int s = 0; s < SEQ; ++s) {
            f4 a = __builtin_nontemporal_load((const f4*)(xp + (size_t)s * Y_DIM));
            m.x = fmaxf(m.x, a.x); m.y = fmaxf(m.y, a.y);
            m.z = fmaxf(m.z, a.z); m.w = fmaxf(m.w, a.w);
        }
        *(f4*)&xs[row][y0] = m;
    }
    __syncthreads();

    {
        const int row = t >> 6;
        const int h0  = (t & 63) * 2;
        float a0 = 0.f, a1 = 0.f;
        const float* Wp = W_common + h0;
        #pragma unroll 8
        for (int k = 0; k < Y_DIM; ++k) {
            float xv = xs[row][k];
            float2 w = *(const float2*)(Wp + (size_t)k * H_DIM);
            a0 += xv * w.x; a1 += xv * w.y;
        }
        float2 bb = *(const float2*)(b_common + h0);
        a0 += bb.x; a1 += bb.y;
        a0 = (a0 > 0.f) ? a0 : (__expf(a0) - 1.f);
        a1 = (a1 > 0.f) ? a1 : (__expf(a1) - 1.f);
        *(float2*)&ys[row][h0] = make_float2(a0, a1);
    }
    __syncthreads();

    for (int j = t; j < ROWS * 120; j += 256) {
        const int row = j / 120;
        const int c   = j - row * 120;
        const float* Wp;
        int stride;
        if (c < 50)       { Wp = W_country + c;        stride = NC_N;  }
        else if (c == 50) { Wp = W_type;               stride = 1;     }
        else if (c < 56)  { Wp = W_taste + (c - 51);   stride = NT_N;  }
        else if (c < 88)  { Wp = W_grape + (c - 56);   stride = E_DIM; }
        else              { Wp = W_aroma + (c - 88);   stride = E_DIM; }
        float acc = 0.f;
        const float* yv = ys[row];
        #pragma unroll 4
        for (int k = 0; k < H_DIM; ++k)
            acc += yv[k] * Wp[(size_t)k * stride];
        const int b = b0 + row;
        if (c < 50) {
            out[O_COUNTRY + (size_t)b * NC_N + c] = acc + b_country[c];
        } else if (c == 50) {
            out[O_TYPE + b] = sigmoidf_(acc + b_type[0]);
        } else if (c < 56) {
            out[O_TASTE + (size_t)b * NT_N + (c - 51)] = sigmoidf_(acc + b_taste[c - 51]);
        } else if (c < 88) {
            yg[row][c - 56] = acc + b_grape[c - 56];
        } else {
            ya[row][c - 88] = acc + b_aroma[c - 88];
        }
    }
    __syncthreads();

    if (t < ROWS * KG_N) {
        const int row  = t >> 3;
        const int gi   = (b0 + row) * KG_N + (t & 7);
        const int idx  = grapes[gi];
        float pred = 0.f;
        if (idx != 0) {
            const float* ep = grapes_emb + (size_t)idx * E_DIM;
            const float* yv = yg[row];
            float acc = 0.f;
            #pragma unroll
            for (int e = 0; e < E_DIM; e += 4) {
                float4 v = *(const float4*)(ep + e);
                acc += yv[e+0]*v.x + yv[e+1]*v.y + yv[e+2]*v.z + yv[e+3]*v.w;
            }
            pred = sigmoidf_(acc);
        }
        out[O_GPRED + gi] = pred;
        out[O_GTRUE + gi] = grapes_scales[gi];
    } else if (t < ROWS * (KG_N + KA_N)) {
        const int j    = t - ROWS * KG_N;
        const int row  = j / KA_N;
        const int ai   = (b0 + row) * KA_N + (j - row * KA_N);
        const float sc = aromas_scales[ai];
        float pred = 0.f;
        if (sc != 0.f) {
            const int idx = aromas[ai];
            const float* ep = aroma_emb + (size_t)idx * E_DIM;
            const float* yv = ya[row];
            float acc = 0.f;
            #pragma unroll
            for (int e = 0; e < E_DIM; e += 4) {
                float4 v = *(const float4*)(ep + e);
                acc += yv[e+0]*v.x + yv[e+1]*v.y + yv[e+2]*v.z + yv[e+3]*v.w;
            }
            pred = sigmoidf_(acc);
        }
        out[O_APRED + ai] = pred;
        out[O_ATRUE + ai] = sc;
    }
}

extern "C" void kernel_launch(void* const* d_in, const int* in_sizes, int n_in,
                              void* d_out, int out_size, void* d_ws, size_t ws_size,
                              hipStream_t stream) {
    (void)in_sizes; (void)n_in; (void)out_size;
    const float* x_enc         = (const float*)d_in[0];
    const int*   grapes        = (const int*)  d_in[1];
    const float* grapes_scales = (const float*)d_in[2];
    const int*   aromas        = (const int*)  d_in[3];
    const float* aromas_scales = (const float*)d_in[4];
    const float* W_common      = (const float*)d_in[5];
    const float* b_common      = (const float*)d_in[6];
    const float* W_country     = (const float*)d_in[7];
    const float* b_country     = (const float*)d_in[8];
    const float* W_type        = (const float*)d_in[9];
    const float* b_type        = (const float*)d_in[10];
    const float* W_taste       = (const float*)d_in[11];
    const float* b_taste       = (const float*)d_in[12];
    const float* W_aroma       = (const float*)d_in[13];
    const float* b_aroma       = (const float*)d_in[14];
    const float* W_grape       = (const float*)d_in[15];
    const float* b_grape       = (const float*)d_in[16];
    const float* grapes_emb    = (const float*)d_in[17];
    const float* aroma_emb     = (const float*)d_in[18];
    float* out = (float*)d_out;

    const size_t pool_bytes = (size_t)B_TOT * Y_DIM * sizeof(float);  // 4 MB
    if (d_ws != nullptr && ws_size >= pool_bytes) {
        float* xpool = (float*)d_ws;
        hipLaunchKernelGGL(maxpool_k, dim3(NB1), dim3(256), 0, stream, x_enc, xpool);
        hipLaunchKernelGGL(heads_k, dim3(NB2), dim3(256), 0, stream,
                           xpool, grapes, grapes_scales, aromas, aromas_scales,
                           W_common, b_common, W_country, b_country, W_type, b_type,
                           W_taste, b_taste, W_aroma, b_aroma, W_grape, b_grape,
                           grapes_emb, aroma_emb, out);
    } else {
        hipLaunchKernelGGL(wine_fused_kernel, dim3(NBLK), dim3(256), 0, stream,
                           x_enc, grapes, grapes_scales, aromas, aromas_scales,
                           W_common, b_common, W_country, b_country, W_type, b_type,
                           W_taste, b_taste, W_aroma, b_aroma, W_grape, b_grape,
                           grapes_emb, aroma_emb, out);
    }
}

// Round 2
// 392.068 us; speedup vs baseline: 1.0500x; 1.0351x over previous
//
#include <hip/hip_runtime.h>
#include <stdint.h>

// Problem constants (reference file)
#define B_TOT 4096
#define SEQ   64
#define Y_DIM 256
#define H_DIM 128
#define E_DIM 32
#define KG_N  8
#define KA_N  20
#define NC_N  50
#define NT_N  5

// Fused: 8 rows/block, 512 threads (8 waves, one per row in phase 1).
// 512 blocks -> 2 blocks/CU -> 16 waves/CU during the x_enc stream.
#define R   8
#define NB  (B_TOT / R)       // 512 blocks

// Output offsets (flat f32, return-order concat)
#define O_COUNTRY 0
#define O_TYPE    (B_TOT * NC_N)                  // 204800
#define O_TASTE   (O_TYPE + B_TOT)                // 208896
#define O_GPRED   (O_TASTE + B_TOT * NT_N)        // 229376
#define O_GTRUE   (O_GPRED + B_TOT * KG_N)        // 262144
#define O_APRED   (O_GTRUE + B_TOT * KG_N)        // 294912
#define O_ATRUE   (O_APRED + B_TOT * KA_N)        // 376832

typedef float f4 __attribute__((ext_vector_type(4)));

__device__ __forceinline__ float sigmoidf_(float x) { return 1.0f / (1.0f + __expf(-x)); }

// ---------------------------------------------------------------------------
// Fused kernel, R=8. Phase 1 is the 268 MB stream (the roofline term);
// phases 2-4 are small and hide under other blocks' phase-1 streaming.
// Single launch, no workspace round-trip.
// ---------------------------------------------------------------------------
__global__ __launch_bounds__(512) void wine_fused8(
    const float* __restrict__ x_enc,          // [B,S,Y] f32
    const int*   __restrict__ grapes,         // [B,KG] i32
    const float* __restrict__ grapes_scales,  // [B,KG] f32
    const int*   __restrict__ aromas,         // [B,KA] i32
    const float* __restrict__ aromas_scales,  // [B,KA] f32
    const float* __restrict__ W_common,  const float* __restrict__ b_common,
    const float* __restrict__ W_country, const float* __restrict__ b_country,
    const float* __restrict__ W_type,    const float* __restrict__ b_type,
    const float* __restrict__ W_taste,   const float* __restrict__ b_taste,
    const float* __restrict__ W_aroma,   const float* __restrict__ b_aroma,
    const float* __restrict__ W_grape,   const float* __restrict__ b_grape,
    const float* __restrict__ grapes_emb,
    const float* __restrict__ aroma_emb,
    float*       __restrict__ out)
{
    __shared__ float xs[R][Y_DIM];            // 8 KB max-pooled x
    __shared__ float ys[R][H_DIM];            // 4 KB elu(common)
    __shared__ float yg[R][E_DIM + 1];
    __shared__ float ya[R][E_DIM + 1];

    const int t  = threadIdx.x;
    const int b0 = blockIdx.x * R;

    // ---------- Phase 1: max over sequence (the 268 MB stream) ----------
    // One wave per row; lane owns one float4 -> each wave-instruction reads
    // a contiguous 1 KiB row segment. Nontemporal: read-once.
    {
        const int row = t >> 6;                  // 0..7
        const int y0  = (t & 63) * 4;
        const float* xp = x_enc + (size_t)(b0 + row) * SEQ * Y_DIM + y0;
        f4 m = { -3.4e38f, -3.4e38f, -3.4e38f, -3.4e38f };
        #pragma unroll 8
        for (int s = 0; s < SEQ; ++s) {
            f4 a = __builtin_nontemporal_load((const f4*)(xp + (size_t)s * Y_DIM));
            m.x = fmaxf(m.x, a.x); m.y = fmaxf(m.y, a.y);
            m.z = fmaxf(m.z, a.z); m.w = fmaxf(m.w, a.w);
        }
        *(f4*)&xs[row][y0] = m;
    }
    __syncthreads();

    // ---------- Phase 2: y = elu(x @ W_common + b_common) ----------
    // thread = (h-col c, 2-row group). Wave reads 256 B of W per k
    // (coalesced, L1/L2-hot: 128 KB matrix, 64 MB aggregate over 512 blocks);
    // x via broadcast ds_read_b128 (all lanes same address -> free).
    {
        const int c  = t & 127;
        const int r0 = (t >> 7) * 2;             // 0,2,4,6
        float a0 = 0.f, a1 = 0.f;
        const float* Wp = W_common + c;
        #pragma unroll 4
        for (int k = 0; k < Y_DIM; k += 4) {
            f4 x0 = *(const f4*)&xs[r0 + 0][k];
            f4 x1 = *(const f4*)&xs[r0 + 1][k];
            float w0 = Wp[(size_t)(k + 0) * H_DIM];
            float w1 = Wp[(size_t)(k + 1) * H_DIM];
            float w2 = Wp[(size_t)(k + 2) * H_DIM];
            float w3 = Wp[(size_t)(k + 3) * H_DIM];
            a0 += x0.x * w0; a0 += x0.y * w1; a0 += x0.z * w2; a0 += x0.w * w3;
            a1 += x1.x * w0; a1 += x1.y * w1; a1 += x1.z * w2; a1 += x1.w * w3;
        }
        const float bb = b_common[c];
        a0 += bb; a1 += bb;
        a0 = (a0 > 0.f) ? a0 : (__expf(a0) - 1.f);
        a1 = (a1 > 0.f) ? a1 : (__expf(a1) - 1.f);
        ys[r0 + 0][c] = a0;
        ys[r0 + 1][c] = a1;
    }
    __syncthreads();

    // ---------- Phase 3: head dots (120 columns per row, 960 jobs) ----------
    // c: [0,50) country | 50 type | [51,56) taste | [56,88) grape | [88,120) aroma
    for (int j = t; j < R * 120; j += 512) {
        const int row = j / 120;
        const int c   = j - row * 120;
        const float* Wp;
        int stride;
        if (c < 50)       { Wp = W_country + c;        stride = NC_N;  }
        else if (c == 50) { Wp = W_type;               stride = 1;     }
        else if (c < 56)  { Wp = W_taste + (c - 51);   stride = NT_N;  }
        else if (c < 88)  { Wp = W_grape + (c - 56);   stride = E_DIM; }
        else              { Wp = W_aroma + (c - 88);   stride = E_DIM; }
        float acc = 0.f;
        const float* yv = ys[row];
        #pragma unroll 4
        for (int k = 0; k < H_DIM; k += 4) {
            f4 y4 = *(const f4*)&yv[k];
            acc += y4.x * Wp[(size_t)(k + 0) * stride];
            acc += y4.y * Wp[(size_t)(k + 1) * stride];
            acc += y4.z * Wp[(size_t)(k + 2) * stride];
            acc += y4.w * Wp[(size_t)(k + 3) * stride];
        }
        const int b = b0 + row;
        if (c < 50) {
            out[O_COUNTRY + (size_t)b * NC_N + c] = acc + b_country[c];
        } else if (c == 50) {
            out[O_TYPE + b] = sigmoidf_(acc + b_type[0]);
        } else if (c < 56) {
            out[O_TASTE + (size_t)b * NT_N + (c - 51)] = sigmoidf_(acc + b_taste[c - 51]);
        } else if (c < 88) {
            yg[row][c - 56] = acc + b_grape[c - 56];
        } else {
            ya[row][c - 88] = acc + b_aroma[c - 88];
        }
    }
    __syncthreads();

    // ---------- Phase 4: ragged gathers ----------
    if (t < R * KG_N) {                          // 64 grape jobs
        const int row  = t >> 3;
        const int gi   = (b0 + row) * KG_N + (t & 7);
        const int idx  = grapes[gi];
        float pred = 0.f;
        if (idx != 0) {
            const float* ep = grapes_emb + (size_t)idx * E_DIM;
            const float* yv = yg[row];
            float acc = 0.f;
            #pragma unroll
            for (int e = 0; e < E_DIM; e += 4) {
                float4 v = *(const float4*)(ep + e);
                acc += yv[e+0]*v.x + yv[e+1]*v.y + yv[e+2]*v.z + yv[e+3]*v.w;
            }
            pred = sigmoidf_(acc);
        }
        out[O_GPRED + gi] = pred;
        out[O_GTRUE + gi] = grapes_scales[gi];   // scales*(scales!=0) == scales, exact
    } else if (t < R * (KG_N + KA_N)) {          // 160 aroma jobs
        const int j    = t - R * KG_N;
        const int row  = j / KA_N;
        const int ai   = (b0 + row) * KA_N + (j - row * KA_N);
        const float sc = aromas_scales[ai];
        float pred = 0.f;
        if (sc != 0.f) {                         // mask = (scales != 0)
            const int idx = aromas[ai];
            const float* ep = aroma_emb + (size_t)idx * E_DIM;
            const float* yv = ya[row];
            float acc = 0.f;
            #pragma unroll
            for (int e = 0; e < E_DIM; e += 4) {
                float4 v = *(const float4*)(ep + e);
                acc += yv[e+0]*v.x + yv[e+1]*v.y + yv[e+2]*v.z + yv[e+3]*v.w;
            }
            pred = sigmoidf_(acc);
        }
        out[O_APRED + ai] = pred;
        out[O_ATRUE + ai] = sc;                  // scales * mask == scales, exact
    }
}

extern "C" void kernel_launch(void* const* d_in, const int* in_sizes, int n_in,
                              void* d_out, int out_size, void* d_ws, size_t ws_size,
                              hipStream_t stream) {
    (void)in_sizes; (void)n_in; (void)d_ws; (void)ws_size; (void)out_size;
    const float* x_enc         = (const float*)d_in[0];
    const int*   grapes        = (const int*)  d_in[1];
    const float* grapes_scales = (const float*)d_in[2];
    const int*   aromas        = (const int*)  d_in[3];
    const float* aromas_scales = (const float*)d_in[4];
    const float* W_common      = (const float*)d_in[5];
    const float* b_common      = (const float*)d_in[6];
    const float* W_country     = (const float*)d_in[7];
    const float* b_country     = (const float*)d_in[8];
    const float* W_type        = (const float*)d_in[9];
    const float* b_type        = (const float*)d_in[10];
    const float* W_taste       = (const float*)d_in[11];
    const float* b_taste       = (const float*)d_in[12];
    const float* W_aroma       = (const float*)d_in[13];
    const float* b_aroma       = (const float*)d_in[14];
    const float* W_grape       = (const float*)d_in[15];
    const float* b_grape       = (const float*)d_in[16];
    const float* grapes_emb    = (const float*)d_in[17];
    const float* aroma_emb     = (const float*)d_in[18];
    float* out = (float*)d_out;

    hipLaunchKernelGGL(wine_fused8, dim3(NB), dim3(512), 0, stream,
                       x_enc, grapes, grapes_scales, aromas, aromas_scales,
                       W_common, b_common, W_country, b_country, W_type, b_type,
                       W_taste, b_taste, W_aroma, b_aroma, W_grape, b_grape,
                       grapes_emb, aroma_emb, out);
}